// Round 9
// baseline (1380.098 us; speedup 1.0000x reference)
//
#include <hip/hip_runtime.h>
#include <hip/hip_bf16.h>
#include <stdint.h>

// ---------------------------------------------------------------------------
// ScRegNet GCN pretrainer fused pipeline, MI355X / gfx950.  Round 9.
// h0 = relu(adj@(x@W0)+b0); h1 = relu(adj@(h0@W1)+b1); emb = adj@(h1@W2)+b2
// logits = gelu(concat(emb[tf],emb[gene])@Wh1+bh1)@Wh2+bh2
//
// R5-R8 nulls isolated the one constant: B-operand re-reads (5 GiB/call of
// Tt served from L3; invisible in FETCH_SIZE which counts HBM only).
// R9: split-K 2 -> 4 so each block's B-chunk (N x K/4 x 2B) = 4 MiB (G2/G4)
// / 2 MiB (G6) fits one XCD's L2.  Block map kc=(b&7)>>1, mb=((b>>3)<<1)|(b&1)
// pins each XCD to ONE kc -> B loaded into L2 once, served at 34.5 TB/s.
// B L3 traffic 5 GiB -> ~50 MiB.  Cost: reduceK<4> (+~25 us Pp traffic).
// gemmAF (fused adj cvt) / gemmA skeletons, G1/G3/G5/head unchanged.
// ---------------------------------------------------------------------------

using f32x4  = __attribute__((ext_vector_type(4))) float;
using bf16x8 = __attribute__((ext_vector_type(8))) __bf16;
using u16x8  = __attribute__((ext_vector_type(8))) unsigned short;
using u16x4  = __attribute__((ext_vector_type(4))) unsigned short;

static __device__ __forceinline__ unsigned short f2bf(float f) {
  unsigned u = __builtin_bit_cast(unsigned, f);
  u += 0x7FFFu + ((u >> 16) & 1u);           // RNE (finite inputs only)
  return (unsigned short)(u >> 16);
}
static __device__ __forceinline__ float bf2f(unsigned short h) {
  unsigned u = ((unsigned)h) << 16;
  return __builtin_bit_cast(float, u);
}
// async global->LDS, 16 B per lane. LDS dest: wave-uniform base + lane*16.
static __device__ __forceinline__ void gload_lds16(const void* g, void* l) {
  __builtin_amdgcn_global_load_lds((__attribute__((address_space(1))) void*)(void*)g,
                                   (__attribute__((address_space(3))) void*)l,
                                   16, 0, 0);
}

// --------------------------- small converters ------------------------------

// out[nf][k] = bf16(in[k][nf])   (weights: [K][Nf] fp32 -> [Nf][K] bf16)
__global__ void tcvt_kernel(const float* __restrict__ in,
                            unsigned short* __restrict__ outp, int K, int Nf) {
  int id = blockIdx.x * 256 + threadIdx.x;
  if (id >= K * Nf) return;
  int k = id % K, nf = id / K;
  outp[id] = f2bf(in[(size_t)k * Nf + nf]);
}

// split-K reduce + bias (+relu) -> bf16
template <int NPART, bool RELU>
__global__ void reduceK_kernel(const float* __restrict__ Pp, const float* __restrict__ bias,
                               unsigned short* __restrict__ outp, int MN, int Nmask) {
  int i = (blockIdx.x * 256 + threadIdx.x) * 4;
  if (i >= MN) return;
  float4 s = *(const float4*)(Pp + i);
#pragma unroll
  for (int p = 1; p < NPART; ++p) {
    float4 v = *(const float4*)(Pp + (size_t)p * MN + i);
    s.x += v.x; s.y += v.y; s.z += v.z; s.w += v.w;
  }
  int col = i & Nmask;
  float r0 = s.x + bias[col + 0];
  float r1 = s.y + bias[col + 1];
  float r2 = s.z + bias[col + 2];
  float r3 = s.w + bias[col + 3];
  if (RELU) {
    r0 = fmaxf(r0, 0.0f); r1 = fmaxf(r1, 0.0f);
    r2 = fmaxf(r2, 0.0f); r3 = fmaxf(r3, 0.0f);
  }
  u16x4 o;
  o[0] = f2bf(r0); o[1] = f2bf(r1); o[2] = f2bf(r2); o[3] = f2bf(r3);
  *(u16x4*)(outp + i) = o;
}

// block mapping shared by gemmAF/gemmA: 512 blocks = 128 mb x 4 kc,
// kc pinned per XCD pair -> each XCD's L2 caches exactly one B K-quarter.
static __device__ __forceinline__ void kmap(int b, int& kc, int& mb) {
  kc = (b & 7) >> 1;
  mb = ((b >> 3) << 1) | (b & 1);
}

// ---------- fused cvt + full-N adj GEMM (gemmAF, G2 only) ------------------
// Pp[kc][M][N] = bf16(A_f32 panel) * Bt^T partials (fp32), AND writes the
// converted panel to adjb (side product; each element staged exactly once:
// mb x kc unique).  BM=128, BN=N=512 (NI=4), split-K=4, grid 512.
template <int NI>
__global__ __launch_bounds__(512, 1)
void gemmAF(const float* __restrict__ A, const unsigned short* __restrict__ Bt,
            float* __restrict__ Pp, unsigned short* __restrict__ adjb,
            int M, int N, int K) {
  __shared__ __align__(16) unsigned short As[2 * 128 * 32];       // 16 KiB
  __shared__ __align__(16) unsigned short Bs[2 * NI * 128 * 32];  // 64 KiB
  const int t = threadIdx.x, l = t & 63, w = t >> 6;

  int kc, mb;
  kmap(blockIdx.x, kc, mb);
  const int Klen = K >> 2;
  const int koff = kc * Klen;
  const int NT = Klen >> 5;                    // 128
  const int fr = l & 15, fq = l >> 4;

  // A fp32 staging: thread t covers row t>>2 (0..127), k0 = (t&3)*8 (8 floats)
  const int arow = t >> 2, ak0 = (t & 3) * 8;
  const float* AgF = A + (size_t)(mb * 128 + arow) * K + koff + ak0;
  unsigned short* AdjW = adjb + (size_t)(mb * 128 + arow) * K + koff + ak0;
  // B staging: gload j covers rows j*128 + (t>>2), k-slot t&3
  const unsigned short* BgR = Bt + (size_t)(t >> 2) * K + koff + (t & 3) * 8;
  unsigned short* BsL = Bs + t * 8;

#define STAGE_B(s, b)                                                         \
  _Pragma("unroll")                                                           \
  for (int j = 0; j < NI; ++j)                                                \
    gload_lds16(BgR + (size_t)(j * 128) * K + (size_t)(s) * 32,               \
                BsL + (b) * NI * 4096 + j * 4096);

  // prologue: tile 0 -> buf 0
  {
    float4 r0 = ((const float4*)AgF)[0];
    float4 r1 = ((const float4*)AgF)[1];
    STAGE_B(0, 0)
    u16x8 v;
    v[0] = f2bf(r0.x); v[1] = f2bf(r0.y); v[2] = f2bf(r0.z); v[3] = f2bf(r0.w);
    v[4] = f2bf(r1.x); v[5] = f2bf(r1.y); v[6] = f2bf(r1.z); v[7] = f2bf(r1.w);
    *(u16x8*)&As[arow * 32 + ak0] = v;
    *(u16x8*)AdjW = v;
  }
  __syncthreads();

  f32x4 acc[8][NI] = {};
  const int aoff = fr * 32 + fq * 8;                    // + mi*512 (+2048 A47)
  const int boff = (w * (NI * 16) + fr) * 32 + fq * 8;  // + ni*512

  for (int tt = 0; tt < NT; ++tt) {
    const int bb = tt & 1;
    bf16x8 a03[4], a47[4], bf[NI];
#pragma unroll
    for (int mi = 0; mi < 4; ++mi)
      a03[mi] = *(const bf16x8*)&As[bb * 4096 + aoff + mi * 512];
#pragma unroll
    for (int ni = 0; ni < NI; ++ni)
      bf[ni] = *(const bf16x8*)&Bs[bb * NI * 4096 + boff + ni * 512];
#pragma unroll
    for (int mi = 0; mi < 4; ++mi)
      a47[mi] = *(const bf16x8*)&As[bb * 4096 + aoff + 2048 + mi * 512];

    float4 r0, r1;
    const bool stg = (tt + 1) < NT;
    if (stg) {
      r0 = ((const float4*)(AgF + (size_t)(tt + 1) * 32))[0];
      r1 = ((const float4*)(AgF + (size_t)(tt + 1) * 32))[1];
      STAGE_B(tt + 1, bb ^ 1)
    }

    __builtin_amdgcn_s_setprio(1);
#pragma unroll
    for (int mi = 0; mi < 4; ++mi)
#pragma unroll
      for (int ni = 0; ni < NI; ++ni)
        acc[mi][ni] = __builtin_amdgcn_mfma_f32_16x16x32_bf16(a03[mi], bf[ni],
                                                              acc[mi][ni], 0, 0, 0);
#pragma unroll
    for (int mi = 0; mi < 4; ++mi)
#pragma unroll
      for (int ni = 0; ni < NI; ++ni)
        acc[mi + 4][ni] = __builtin_amdgcn_mfma_f32_16x16x32_bf16(a47[mi], bf[ni],
                                                                  acc[mi + 4][ni], 0, 0, 0);
    __builtin_amdgcn_s_setprio(0);

    if (stg) {
      u16x8 v;
      v[0] = f2bf(r0.x); v[1] = f2bf(r0.y); v[2] = f2bf(r0.z); v[3] = f2bf(r0.w);
      v[4] = f2bf(r1.x); v[5] = f2bf(r1.y); v[6] = f2bf(r1.z); v[7] = f2bf(r1.w);
      *(u16x8*)&As[(bb ^ 1) * 4096 + arow * 32 + ak0] = v;
      *(u16x8*)(AdjW + (size_t)(tt + 1) * 32) = v;
    }
    __syncthreads();   // drains B gloads + orders LDS for next tile
  }
#undef STAGE_B

  float* C = Pp + (size_t)kc * M * N;
  const int growb = mb * 128 + fq * 4;
  const int gcolb = w * (NI * 16) + fr;
#pragma unroll
  for (int mi = 0; mi < 8; ++mi) {
    int row = growb + mi * 16;
#pragma unroll
    for (int ni = 0; ni < NI; ++ni) {
      int col = gcolb + ni * 16;
      f32x4 v = acc[mi][ni];
#pragma unroll
      for (int r = 0; r < 4; ++r)
        C[(size_t)(row + r) * N + col] = v[r];
    }
  }
}

// ----------------- full-N adj GEMM (gemmA, BM=128, BN=N) -------------------
// split-K=4, grid 512, kc-per-XCD-pair mapping (B K-quarter L2-resident).
template <int NI>
__global__ __launch_bounds__(512, 1)
void gemmA(const unsigned short* __restrict__ A, const unsigned short* __restrict__ Bt,
           float* __restrict__ Pp, int M, int N, int K) {
  constexpr int NL = 1 + NI;                     // gloads per tile
  __shared__ __align__(16) unsigned short As[3 * 128 * 32];      // 24 KiB
  __shared__ __align__(16) unsigned short Bs[3 * NI * 128 * 32]; // 96/48 KiB
  const int t = threadIdx.x, l = t & 63, w = t >> 6;

  int kc, mb;
  kmap(blockIdx.x, kc, mb);
  const int Klen = K >> 2;
  const int koff = kc * Klen;
  const int NT = Klen >> 5;                      // 128
  const int fr = l & 15, fq = l >> 4;

  const unsigned short* AgR = A  + (size_t)(mb * 128 + (t >> 2)) * K + koff + (t & 3) * 8;
  const unsigned short* BgR = Bt + (size_t)(t >> 2) * K + koff + (t & 3) * 8;
  unsigned short* AsL = As + t * 8;
  unsigned short* BsL = Bs + t * 8;

#define STAGE_A(s, b)  gload_lds16(AgR + (size_t)(s) * 32, AsL + (b) * 4096);
#define STAGE_B(s, b)                                                         \
  _Pragma("unroll")                                                           \
  for (int j = 0; j < NI; ++j)                                                \
    gload_lds16(BgR + (size_t)(j * 128) * K + (size_t)(s) * 32,               \
                BsL + (b) * NI * 4096 + j * 4096);

  STAGE_A(0, 0) STAGE_B(0, 0)
  STAGE_A(1, 1) STAGE_B(1, 1)
  asm volatile("s_waitcnt vmcnt(%0)" :: "i"(NL) : "memory");
  __builtin_amdgcn_sched_barrier(0);
  __builtin_amdgcn_s_barrier();

  f32x4 acc[8][NI] = {};
  const int aoff = fr * 32 + fq * 8;
  const int boff = (w * (NI * 16) + fr) * 32 + fq * 8;

  int bb = 0, sb = 2;
  for (int tt = 0; tt < NT; ++tt) {
    const bool stg = (tt + 2) < NT;
    bf16x8 a03[4], a47[4], bf[NI];
#pragma unroll
    for (int mi = 0; mi < 4; ++mi)
      a03[mi] = *(const bf16x8*)&As[bb * 4096 + aoff + mi * 512];
#pragma unroll
    for (int ni = 0; ni < NI; ++ni)
      bf[ni] = *(const bf16x8*)&Bs[bb * NI * 4096 + boff + ni * 512];
#pragma unroll
    for (int mi = 0; mi < 4; ++mi)
      a47[mi] = *(const bf16x8*)&As[bb * 4096 + aoff + 2048 + mi * 512];
    if (stg) { STAGE_A(tt + 2, sb) }
    asm volatile("s_waitcnt lgkmcnt(4)" ::: "memory");
    __builtin_amdgcn_sched_barrier(0);
    __builtin_amdgcn_s_setprio(1);
#pragma unroll
    for (int mi = 0; mi < 4; ++mi)
#pragma unroll
      for (int ni = 0; ni < NI; ++ni)
        acc[mi][ni] = __builtin_amdgcn_mfma_f32_16x16x32_bf16(a03[mi], bf[ni],
                                                              acc[mi][ni], 0, 0, 0);
    __builtin_amdgcn_s_setprio(0);
    asm volatile("s_waitcnt lgkmcnt(0)" ::: "memory");
    __builtin_amdgcn_sched_barrier(0);
    __builtin_amdgcn_s_setprio(1);
#pragma unroll
    for (int mi = 0; mi < 4; ++mi)
#pragma unroll
      for (int ni = 0; ni < NI; ++ni)
        acc[mi + 4][ni] = __builtin_amdgcn_mfma_f32_16x16x32_bf16(a47[mi], bf[ni],
                                                                  acc[mi + 4][ni], 0, 0, 0);
    __builtin_amdgcn_s_setprio(0);
    if (stg) { STAGE_B(tt + 2, sb) }
    if (stg) {
      asm volatile("s_waitcnt vmcnt(%0)" :: "i"(NL) : "memory");
    } else {
      asm volatile("s_waitcnt vmcnt(0)" ::: "memory");
    }
    __builtin_amdgcn_sched_barrier(0);
    __builtin_amdgcn_s_barrier();
    bb = (bb == 2) ? 0 : bb + 1;
    sb = (sb == 2) ? 0 : sb + 1;
  }
#undef STAGE_B
#undef STAGE_A

  float* C = Pp + (size_t)kc * M * N;
  const int growb = mb * 128 + fq * 4;
  const int gcolb = w * (NI * 16) + fr;
#pragma unroll
  for (int mi = 0; mi < 8; ++mi) {
    int row = growb + mi * 16;
#pragma unroll
    for (int ni = 0; ni < NI; ++ni) {
      int col = gcolb + ni * 16;
      f32x4 v = acc[mi][ni];
#pragma unroll
      for (int r = 0; r < 4; ++r)
        C[(size_t)(row + r) * N + col] = v[r];
    }
  }
}

// ------------------------------ main GEMM ----------------------------------
// (unchanged 2-phase kernel; used for G1/G3/G5 + no-adjb fallback)
template <int EP, bool ABF16>
__global__ __launch_bounds__(256, 2)
void gemm_bt(const void* __restrict__ Av, const unsigned short* __restrict__ Bt,
             void* __restrict__ Cout, const float* __restrict__ bias,
             int M, int N, int K, int nbx, int Klen) {
  __shared__ __align__(16) unsigned short As[128 * 64];
  __shared__ __align__(16) unsigned short Bs[128 * 64];
  const int t = threadIdx.x;
  const int l = t & 63;
  const int w = t >> 6;

  int wg = blockIdx.x;
  const int cpx = gridDim.x >> 3;
  wg = (wg & 7) * cpx + (wg >> 3);
  const int mb = wg / nbx, nb = wg % nbx;
  const int kc = blockIdx.y;
  const int koff = kc * Klen;

  const int wr = w >> 1, wc = w & 1;
  f32x4 acc[4][4] = {};

  const int srow = w * 8 + (l >> 3);
  const int sk0  = 8 * ((l & 7) ^ (l >> 3));
  const unsigned short* Bg = Bt + (size_t)(nb * 128 + srow) * K + koff + sk0;
  unsigned short* BsL = Bs + w * 512 + l * 8;
  unsigned short* AsL = As + w * 512 + l * 8;

  const unsigned short* Ag16 = nullptr;
  const float* Ag32 = nullptr;
  unsigned short* AsWr = nullptr;
  int ak = 0, axm = 0;
  if constexpr (ABF16) {
    Ag16 = (const unsigned short*)Av + (size_t)(mb * 128 + srow) * K + koff + sk0;
  } else {
    const int ar = t >> 1;
    ak = (t & 1) * 32;
    axm = (ar & 7) << 3;
    Ag32 = (const float*)Av + (size_t)(mb * 128 + ar) * K + koff + ak;
    AsWr = As + ar * 64;
  }

  const int fr = l & 15, fq = l >> 4;
  const int rxor = (fr & 7) << 3;

  const int steps = Klen >> 6;
  for (int kb = 0; kb < steps; ++kb) {
#pragma unroll
    for (int i = 0; i < 4; ++i)
      gload_lds16(Bg + (size_t)i * 32 * K, BsL + i * 2048);
    Bg += 64;
    if constexpr (ABF16) {
#pragma unroll
      for (int i = 0; i < 4; ++i)
        gload_lds16(Ag16 + (size_t)i * 32 * K, AsL + i * 2048);
      Ag16 += 64;
    } else {
#pragma unroll
      for (int q = 0; q < 4; ++q) {
        float4 c0 = ((const float4*)Ag32)[q * 2];
        float4 c1 = ((const float4*)Ag32)[q * 2 + 1];
        u16x8 v;
        v[0] = f2bf(c0.x); v[1] = f2bf(c0.y); v[2] = f2bf(c0.z); v[3] = f2bf(c0.w);
        v[4] = f2bf(c1.x); v[5] = f2bf(c1.y); v[6] = f2bf(c1.z); v[7] = f2bf(c1.w);
        *(u16x8*)&AsWr[(ak + q * 8) ^ axm] = v;
      }
      Ag32 += 64;
    }
    __syncthreads();

    bf16x8 af[2][4], bfr[2][4];
#pragma unroll
    for (int kk = 0; kk < 2; ++kk) {
#pragma unroll
      for (int mi = 0; mi < 4; ++mi) {
        int arow = wr * 64 + mi * 16 + fr;
        af[kk][mi] = *(const bf16x8*)&As[arow * 64 + ((kk * 32 + fq * 8) ^ rxor)];
      }
#pragma unroll
      for (int ni = 0; ni < 4; ++ni) {
        int brow = wc * 64 + ni * 16 + fr;
        bfr[kk][ni] = *(const bf16x8*)&Bs[brow * 64 + ((kk * 32 + fq * 8) ^ rxor)];
      }
    }
#pragma unroll
    for (int kk = 0; kk < 2; ++kk)
#pragma unroll
      for (int mi = 0; mi < 4; ++mi)
#pragma unroll
        for (int ni = 0; ni < 4; ++ni)
          acc[mi][ni] = __builtin_amdgcn_mfma_f32_16x16x32_bf16(af[kk][mi], bfr[kk][ni],
                                                                acc[mi][ni], 0, 0, 0);
    __syncthreads();
  }

  const int r0 = fq * 4;
  const int c0 = fr;
  const int growb = mb * 128 + wr * 64 + r0;
  const int gcolb = nb * 128 + wc * 64 + c0;
  if constexpr (EP == 0) {
    unsigned short* Ct = (unsigned short*)Cout;  // [N][M] bf16
#pragma unroll
    for (int ni = 0; ni < 4; ++ni) {
      int col = gcolb + ni * 16;
#pragma unroll
      for (int mi = 0; mi < 4; ++mi) {
        int row = growb + mi * 16;
        f32x4 v = acc[mi][ni];
        u16x4 o;
        o[0] = f2bf(v[0]); o[1] = f2bf(v[1]); o[2] = f2bf(v[2]); o[3] = f2bf(v[3]);
        *(u16x4*)&Ct[(size_t)col * M + row] = o;
      }
    }
  } else if constexpr (EP == 1) {
    unsigned short* C = (unsigned short*)Cout;  // [M][N] bf16, relu(.+bias)
#pragma unroll
    for (int ni = 0; ni < 4; ++ni) {
      int col = gcolb + ni * 16;
      float b = bias[col];
#pragma unroll
      for (int mi = 0; mi < 4; ++mi) {
        int row = growb + mi * 16;
        f32x4 v = acc[mi][ni];
#pragma unroll
        for (int r = 0; r < 4; ++r)
          C[(size_t)(row + r) * N + col] = f2bf(fmaxf(v[r] + b, 0.0f));
      }
    }
  } else {  // EP == 3: split-K fp32 partial
    float* C = (float*)Cout + (size_t)kc * M * N;
#pragma unroll
    for (int ni = 0; ni < 4; ++ni) {
      int col = gcolb + ni * 16;
#pragma unroll
      for (int mi = 0; mi < 4; ++mi) {
        int row = growb + mi * 16;
        f32x4 v = acc[mi][ni];
#pragma unroll
        for (int r = 0; r < 4; ++r)
          C[(size_t)(row + r) * N + col] = v[r];
      }
    }
  }
}

// ------------------------------ head kernel --------------------------------
__global__ __launch_bounds__(256, 2)
void head_kernel(const unsigned short* __restrict__ EMB, const int* __restrict__ tf,
                 const int* __restrict__ gi, const unsigned short* __restrict__ Wh1t,
                 const float* __restrict__ bh1, const float* __restrict__ Wh2,
                 const float* __restrict__ bh2, float* __restrict__ out, int P) {
  __shared__ __align__(16) union SU {
    struct { unsigned short As[64 * 64]; unsigned short Bs[256 * 64]; } s;
    unsigned short hdn[64 * 264];
  } u;
  __shared__ float wh2s[256 * 3];
  const int t = threadIdx.x, l = t & 63, w = t >> 6;
  const int pb = blockIdx.x;

  wh2s[t]       = Wh2[t];
  wh2s[t + 256] = Wh2[t + 256];
  wh2s[t + 512] = Wh2[t + 512];

  const int srow = w * 8 + (l >> 3);
  const int sk0  = 8 * ((l & 7) ^ (l >> 3));
  size_t tfo[2], gio[2];
#pragma unroll
  for (int i = 0; i < 2; ++i) {
    int p = pb * 64 + i * 32 + srow;
    if (p >= P) p = P - 1;
    tfo[i] = (size_t)tf[p] * 256;
    gio[i] = (size_t)gi[p] * 256;
  }
  const unsigned short* BgB = Wh1t + (size_t)srow * 512 + sk0;
  unsigned short* AsL = u.s.As + w * 512 + l * 8;
  unsigned short* BsL = u.s.Bs + w * 512 + l * 8;

  const int fr = l & 15, fq = l >> 4;
  const int rxor = (fr & 7) << 3;

  f32x4 acc[4][4] = {};
  for (int kb = 0; kb < 8; ++kb) {
    const int klo = (kb & 3) * 64 + sk0;
#pragma unroll
    for (int i = 0; i < 2; ++i)
      gload_lds16(EMB + ((kb < 4) ? tfo[i] : gio[i]) + klo, AsL + i * 2048);
#pragma unroll
    for (int i = 0; i < 8; ++i)
      gload_lds16(BgB + (size_t)i * 32 * 512 + kb * 64, BsL + i * 2048);
    __syncthreads();

    bf16x8 af[2][4], bfr[2][4];
#pragma unroll
    for (int kk = 0; kk < 2; ++kk) {
#pragma unroll
      for (int mi = 0; mi < 4; ++mi) {
        int arow = mi * 16 + fr;
        af[kk][mi] = *(const bf16x8*)&u.s.As[arow * 64 + ((kk * 32 + fq * 8) ^ rxor)];
      }
#pragma unroll
      for (int ni = 0; ni < 4; ++ni) {
        int brow = w * 64 + ni * 16 + fr;
        bfr[kk][ni] = *(const bf16x8*)&u.s.Bs[brow * 64 + ((kk * 32 + fq * 8) ^ rxor)];
      }
    }
#pragma unroll
    for (int kk = 0; kk < 2; ++kk)
#pragma unroll
      for (int mi = 0; mi < 4; ++mi)
#pragma unroll
        for (int ni = 0; ni < 4; ++ni)
          acc[mi][ni] = __builtin_amdgcn_mfma_f32_16x16x32_bf16(af[kk][mi], bfr[kk][ni],
                                                                acc[mi][ni], 0, 0, 0);
    __syncthreads();
  }

  const int r0 = fq * 4, c0 = fr;
#pragma unroll
  for (int ni = 0; ni < 4; ++ni) {
    int col = w * 64 + ni * 16 + c0;
    float b = bh1[col];
#pragma unroll
    for (int mi = 0; mi < 4; ++mi) {
      int row = mi * 16 + r0;
      f32x4 v = acc[mi][ni];
#pragma unroll
      for (int r = 0; r < 4; ++r) {
        float xv = v[r] + b;
        float g = 0.5f * xv * (1.0f + erff(xv * 0.70710678118f));
        u.hdn[(row + r) * 264 + col] = f2bf(g);
      }
    }
  }
  __syncthreads();

  const int pl = w * 16 + (l >> 2);
  const int pg = pb * 64 + pl;
  const int ks = (l & 3) * 64;
  float a0 = 0.f, a1 = 0.f, a2 = 0.f;
  const unsigned short* hr = u.hdn + pl * 264 + ks;
#pragma unroll
  for (int kq = 0; kq < 8; ++kq) {
    u16x8 hv = *(const u16x8*)(hr + kq * 8);
#pragma unroll
    for (int j = 0; j < 8; ++j) {
      float h = bf2f(hv[j]);
      int k = ks + kq * 8 + j;
      a0 = fmaf(h, wh2s[k * 3 + 0], a0);
      a1 = fmaf(h, wh2s[k * 3 + 1], a1);
      a2 = fmaf(h, wh2s[k * 3 + 2], a2);
    }
  }
  a0 += __shfl_xor(a0, 1); a0 += __shfl_xor(a0, 2);
  a1 += __shfl_xor(a1, 1); a1 += __shfl_xor(a1, 2);
  a2 += __shfl_xor(a2, 1); a2 += __shfl_xor(a2, 2);
  if ((l & 3) == 0 && pg < P) {
    out[(size_t)pg * 3 + 0] = a0 + bh2[0];
    out[(size_t)pg * 3 + 1] = a1 + bh2[1];
    out[(size_t)pg * 3 + 2] = a2 + bh2[2];
  }
}

// ------------------------------- launcher ----------------------------------

extern "C" void kernel_launch(void* const* d_in, const int* in_sizes, int n_in,
                              void* d_out, int out_size, void* d_ws, size_t ws_size,
                              hipStream_t stream) {
  const float* x   = (const float*)d_in[0];
  const float* adj = (const float*)d_in[1];
  const int*   tf  = (const int*)d_in[2];
  const int*   gi  = (const int*)d_in[3];
  const float* W0  = (const float*)d_in[4];
  const float* b0  = (const float*)d_in[5];
  const float* W1  = (const float*)d_in[6];
  const float* b1  = (const float*)d_in[7];
  const float* W2  = (const float*)d_in[8];
  const float* b2  = (const float*)d_in[9];
  const float* Wh1 = (const float*)d_in[10];
  const float* bh1 = (const float*)d_in[11];
  const float* Wh2 = (const float*)d_in[12];
  const float* bh2 = (const float*)d_in[13];
  float* out = (float*)d_out;

  const int NN = 16384;
  const int P = in_sizes[2];  // 100000

  char* ws = (char*)d_ws;
  size_t off = 0;
  auto alloc = [&](size_t bytes) -> char* {
    char* p = ws + off;
    off += (bytes + 255) & ~(size_t)255;
    return p;
  };
  unsigned short* W0t  = (unsigned short*)alloc((size_t)512 * 1024 * 2);
  unsigned short* W1t  = (unsigned short*)alloc((size_t)512 * 512 * 2);
  unsigned short* W2t  = (unsigned short*)alloc((size_t)256 * 512 * 2);
  unsigned short* Wh1t = (unsigned short*)alloc((size_t)256 * 512 * 2);
  unsigned short* Tt   = (unsigned short*)alloc((size_t)512 * NN * 2);  // T0t/T1t/T2t
  unsigned short* H    = (unsigned short*)alloc((size_t)NN * 512 * 2);  // H0/H1 bf16
  unsigned short* EMB  = (unsigned short*)alloc((size_t)NN * 256 * 2);
  float*          Pp   = (float*)alloc((size_t)4 * NN * 512 * 4);       // split-K partials (128 MiB)
  size_t base_end = off;

  bool useAdjB = false;
  unsigned short* adjb = nullptr;
  if (ws_size >= base_end + (size_t)NN * NN * 2) {
    adjb = (unsigned short*)alloc((size_t)NN * NN * 2);
    useAdjB = true;
  }

  // weight transpose+convert (tiny)
  tcvt_kernel<<<dim3((1024 * 512 + 255) / 256), 256, 0, stream>>>(W0, W0t, 1024, 512);
  tcvt_kernel<<<dim3((512 * 512 + 255) / 256), 256, 0, stream>>>(W1, W1t, 512, 512);
  tcvt_kernel<<<dim3((512 * 256 + 255) / 256), 256, 0, stream>>>(W2, W2t, 512, 256);
  tcvt_kernel<<<dim3((512 * 256 + 255) / 256), 256, 0, stream>>>(Wh1, Wh1t, 512, 256);

  // G1: T0t = (x @ W0)^T                       [512][16384] bf16
  gemm_bt<0, false><<<dim3(512), 256, 0, stream>>>(x, W0t, Tt, nullptr,
                                                   NN, 512, 1024, 4, 1024);
  // G2: H0 = relu(adj @ T0 + b0)  [fused fp32-adj convert + adjb side-write]
  if (useAdjB) {
    gemmAF<4><<<dim3(512), 512, 0, stream>>>(adj, Tt, Pp, adjb, NN, 512, NN);
    reduceK_kernel<4, true><<<dim3(8192), 256, 0, stream>>>(Pp, b0, H, NN * 512, 511);
  } else {
    gemm_bt<1, false><<<dim3(512), 256, 0, stream>>>(adj, Tt, H, b0,
                                                     NN, 512, NN, 4, NN);
  }
  // G3: T1t = (H0 @ W1)^T
  gemm_bt<0, true><<<dim3(512), 256, 0, stream>>>(H, W1t, Tt, nullptr,
                                                  NN, 512, 512, 4, 512);
  // G4: H1 = relu(adj @ T1 + b1)
  if (useAdjB) {
    gemmA<4><<<dim3(512), 512, 0, stream>>>(adjb, Tt, Pp, NN, 512, NN);
    reduceK_kernel<4, true><<<dim3(8192), 256, 0, stream>>>(Pp, b1, H, NN * 512, 511);
  } else {
    gemm_bt<1, false><<<dim3(512), 256, 0, stream>>>(adj, Tt, H, b1,
                                                     NN, 512, NN, 4, NN);
  }
  // G5: T2t = (H1 @ W2)^T                      [256][16384] bf16
  gemm_bt<0, true><<<dim3(256), 256, 0, stream>>>(H, W2t, Tt, nullptr,
                                                  NN, 256, 512, 2, 512);
  // G6: EMB = adj @ T2 + b2                    split-K=4 fp32 partials
  if (useAdjB) {
    gemmA<2><<<dim3(512), 512, 0, stream>>>(adjb, Tt, Pp, NN, 256, NN);
    reduceK_kernel<4, false><<<dim3(4096), 256, 0, stream>>>(Pp, b2, EMB, NN * 256, 255);
  } else {
    gemm_bt<3, false><<<dim3(256, 2), 256, 0, stream>>>(adj, Tt, Pp, nullptr,
                                                        NN, 256, NN, 2, NN / 2);
    reduceK_kernel<2, false><<<dim3(4096), 256, 0, stream>>>(Pp, b2, EMB, NN * 256, 255);
  }
  // head: gather + MLP + logits
  head_kernel<<<dim3((P + 63) / 64), 256, 0, stream>>>(EMB, tf, gi, Wh1t, bh1,
                                                       Wh2, bh2, out, P);
}

// Round 10
// 1304.521 us; speedup vs baseline: 1.0579x; 1.0579x over previous
//
#include <hip/hip_runtime.h>
#include <hip/hip_bf16.h>
#include <stdint.h>

// ---------------------------------------------------------------------------
// ScRegNet GCN pretrainer fused pipeline, MI355X / gfx950.  Round 10.
// h0 = relu(adj@(x@W0)+b0); h1 = relu(adj@(h0@W1)+b1); emb = adj@(h1@W2)+b2
// logits = gelu(concat(emb[tf],emb[gene])@Wh1+bh1)@Wh2+bh2
//
// R9 rocprof: gemmAF = 680us alone, SQ_LDS_BANK_CONFLICT 2.5e7, MfmaUtil 17%,
// hbm 24% -> stall-bound.  Two proven defects fixed here:
//  1. LDS 16B-slot XOR swizzle (slot ^= (row>>1)&3) for the [*][32] bf16
//     tiles: the linear layout put 16 lanes of every ds_read_b128 on 2 banks
//     (8-way conflict).  Applied rule-#21 style: pre-swizzled GLOBAL source
//     for global_load_lds, swizzled ds_write slot for reg-staged A, same XOR
//     on the read side.  Applied to gemmAF AND gemmA.
//  2. gemmAF per-tile __syncthreads (vmcnt(0) drain incl. adjb store-acks)
//     -> raw s_barrier + counted s_waitcnt vmcnt(1) lgkmcnt(0) (in-order
//     vmem retirement: all 4 B-gloads done; only this tile's store rides).
//  Also: gemmAF back to grid 256 / split-K=2 (single pass, Pp halved).
// ---------------------------------------------------------------------------

using f32x4  = __attribute__((ext_vector_type(4))) float;
using bf16x8 = __attribute__((ext_vector_type(8))) __bf16;
using u16x8  = __attribute__((ext_vector_type(8))) unsigned short;
using u16x4  = __attribute__((ext_vector_type(4))) unsigned short;

static __device__ __forceinline__ unsigned short f2bf(float f) {
  unsigned u = __builtin_bit_cast(unsigned, f);
  u += 0x7FFFu + ((u >> 16) & 1u);           // RNE (finite inputs only)
  return (unsigned short)(u >> 16);
}
static __device__ __forceinline__ float bf2f(unsigned short h) {
  unsigned u = ((unsigned)h) << 16;
  return __builtin_bit_cast(float, u);
}
// async global->LDS, 16 B per lane. LDS dest: wave-uniform base + lane*16.
static __device__ __forceinline__ void gload_lds16(const void* g, void* l) {
  __builtin_amdgcn_global_load_lds((__attribute__((address_space(1))) void*)(void*)g,
                                   (__attribute__((address_space(3))) void*)l,
                                   16, 0, 0);
}

// --------------------------- small converters ------------------------------

// out[nf][k] = bf16(in[k][nf])   (weights: [K][Nf] fp32 -> [Nf][K] bf16)
__global__ void tcvt_kernel(const float* __restrict__ in,
                            unsigned short* __restrict__ outp, int K, int Nf) {
  int id = blockIdx.x * 256 + threadIdx.x;
  if (id >= K * Nf) return;
  int k = id % K, nf = id / K;
  outp[id] = f2bf(in[(size_t)k * Nf + nf]);
}

// split-K reduce + bias (+relu) -> bf16
template <int NPART, bool RELU>
__global__ void reduceK_kernel(const float* __restrict__ Pp, const float* __restrict__ bias,
                               unsigned short* __restrict__ outp, int MN, int Nmask) {
  int i = (blockIdx.x * 256 + threadIdx.x) * 4;
  if (i >= MN) return;
  float4 s = *(const float4*)(Pp + i);
#pragma unroll
  for (int p = 1; p < NPART; ++p) {
    float4 v = *(const float4*)(Pp + (size_t)p * MN + i);
    s.x += v.x; s.y += v.y; s.z += v.z; s.w += v.w;
  }
  int col = i & Nmask;
  float r0 = s.x + bias[col + 0];
  float r1 = s.y + bias[col + 1];
  float r2 = s.z + bias[col + 2];
  float r3 = s.w + bias[col + 3];
  if (RELU) {
    r0 = fmaxf(r0, 0.0f); r1 = fmaxf(r1, 0.0f);
    r2 = fmaxf(r2, 0.0f); r3 = fmaxf(r3, 0.0f);
  }
  u16x4 o;
  o[0] = f2bf(r0); o[1] = f2bf(r1); o[2] = f2bf(r2); o[3] = f2bf(r3);
  *(u16x4*)(outp + i) = o;
}

// ---------- fused cvt + full-N adj GEMM (gemmAF, G2 only) ------------------
// Pp[kc][M][N] = bf16(A_f32 panel) * Bt^T partials (fp32), AND writes the
// converted panel to adjb (side product; each element staged exactly once).
// BM=128, BN=N=512 (NI=4), split-K=2, grid 256 (1 block/CU, single pass).
// LDS double-buffer, swizzled tiles; raw barrier + counted vmcnt(1).
template <int NI>
__global__ __launch_bounds__(512, 1)
void gemmAF(const float* __restrict__ A, const unsigned short* __restrict__ Bt,
            float* __restrict__ Pp, unsigned short* __restrict__ adjb,
            int M, int N, int K) {
  __shared__ __align__(16) unsigned short As[2 * 128 * 32];       // 16 KiB
  __shared__ __align__(16) unsigned short Bs[2 * NI * 128 * 32];  // 64 KiB
  const int t = threadIdx.x, l = t & 63, w = t >> 6;

  const int wg = (blockIdx.x & 7) * 32 + (blockIdx.x >> 3);   // kc-per-XCD
  const int kc = wg >> 7;
  const int mb = wg & 127;
  const int Klen = K >> 1;
  const int koff = kc * Klen;
  const int NT = Klen >> 5;                  // 256
  const int fr = l & 15, fq = l >> 4;
  const int sx = ((fr >> 1) & 3) << 3;       // read-side slot XOR (elements)

  // staging: thread t -> row t>>2, G-slot t&3; swizzled phys slot (t&3)^((t>>3)&3)
  const int arow = t >> 2, ak0 = (t & 3) * 8;
  const int swz = (((t & 3) ^ ((t >> 3) & 3))) * 8;
  const float* AgF = A + (size_t)(mb * 128 + arow) * K + koff + ak0;
  unsigned short* AdjW = adjb + (size_t)(mb * 128 + arow) * K + koff + ak0;
  const unsigned short* BgR = Bt + (size_t)arow * K + koff + swz;  // pre-swz src
  unsigned short* BsL = Bs + t * 8;          // linear dest (gload_lds law)
  unsigned short* AsW = As + arow * 32 + swz;

#define STAGE_B(s, b)                                                         \
  _Pragma("unroll")                                                           \
  for (int j = 0; j < NI; ++j)                                                \
    gload_lds16(BgR + (size_t)(j * 128) * K + (size_t)(s) * 32,               \
                BsL + (b) * NI * 4096 + j * 4096);

  // prologue: tile 0 -> buf 0 (drain once)
  {
    float4 p0 = ((const float4*)AgF)[0];
    float4 p1 = ((const float4*)AgF)[1];
    STAGE_B(0, 0)
    u16x8 v;
    v[0] = f2bf(p0.x); v[1] = f2bf(p0.y); v[2] = f2bf(p0.z); v[3] = f2bf(p0.w);
    v[4] = f2bf(p1.x); v[5] = f2bf(p1.y); v[6] = f2bf(p1.z); v[7] = f2bf(p1.w);
    *(u16x8*)AsW = v;
    *(u16x8*)AdjW = v;
  }
  asm volatile("s_waitcnt vmcnt(0) lgkmcnt(0)" ::: "memory");
  __builtin_amdgcn_sched_barrier(0);
  __builtin_amdgcn_s_barrier();

  f32x4 acc[8][NI] = {};
  const int aoff = fr * 32;                       // + mi*512 (+2048 for a47)
  const int boff = (w * (NI * 16) + fr) * 32;     // + ni*512

  for (int tt = 0; tt < NT; ++tt) {
    const int bb = tt & 1;
    bf16x8 a03[4], a47[4], bf[NI];
#pragma unroll
    for (int mi = 0; mi < 4; ++mi)
      a03[mi] = *(const bf16x8*)&As[bb * 4096 + aoff + mi * 512 + ((fq * 8) ^ sx)];
#pragma unroll
    for (int ni = 0; ni < NI; ++ni)
      bf[ni] = *(const bf16x8*)&Bs[bb * NI * 4096 + boff + ni * 512 + ((fq * 8) ^ sx)];
#pragma unroll
    for (int mi = 0; mi < 4; ++mi)
      a47[mi] = *(const bf16x8*)&As[bb * 4096 + aoff + 2048 + mi * 512 + ((fq * 8) ^ sx)];

    float4 p0, p1;
    const bool stg = (tt + 1) < NT;
    if (stg) {
      p0 = ((const float4*)(AgF + (size_t)(tt + 1) * 32))[0];
      p1 = ((const float4*)(AgF + (size_t)(tt + 1) * 32))[1];
      STAGE_B(tt + 1, bb ^ 1)
    }
    asm volatile("s_waitcnt lgkmcnt(0)" ::: "memory");
    __builtin_amdgcn_sched_barrier(0);
    __builtin_amdgcn_s_setprio(1);
#pragma unroll
    for (int mi = 0; mi < 4; ++mi)
#pragma unroll
      for (int ni = 0; ni < NI; ++ni)
        acc[mi][ni] = __builtin_amdgcn_mfma_f32_16x16x32_bf16(a03[mi], bf[ni],
                                                              acc[mi][ni], 0, 0, 0);
#pragma unroll
    for (int mi = 0; mi < 4; ++mi)
#pragma unroll
      for (int ni = 0; ni < NI; ++ni)
        acc[mi + 4][ni] = __builtin_amdgcn_mfma_f32_16x16x32_bf16(a47[mi], bf[ni],
                                                                  acc[mi + 4][ni], 0, 0, 0);
    __builtin_amdgcn_s_setprio(0);

    if (stg) {
      u16x8 v;
      v[0] = f2bf(p0.x); v[1] = f2bf(p0.y); v[2] = f2bf(p0.z); v[3] = f2bf(p0.w);
      v[4] = f2bf(p1.x); v[5] = f2bf(p1.y); v[6] = f2bf(p1.z); v[7] = f2bf(p1.w);
      *(u16x8*)(AsW + (bb ^ 1) * 4096) = v;
      *(u16x8*)(AdjW + (size_t)(tt + 1) * 32) = v;
    }
    // counted boundary: in-order vmem retirement => <=1 outstanding means all
    // 4 B-gloads of tile tt+1 are done; only this tile's adjb store rides.
    asm volatile("s_waitcnt vmcnt(1) lgkmcnt(0)" ::: "memory");
    __builtin_amdgcn_sched_barrier(0);
    __builtin_amdgcn_s_barrier();
  }
#undef STAGE_B

  // epilogue: fp32 partials. C/D layout: col = lane&15, row = (lane>>4)*4+r
  float* C = Pp + (size_t)kc * M * N;
  const int growb = mb * 128 + fq * 4;
  const int gcolb = w * (NI * 16) + fr;
#pragma unroll
  for (int mi = 0; mi < 8; ++mi) {
    int row = growb + mi * 16;
#pragma unroll
    for (int ni = 0; ni < NI; ++ni) {
      int col = gcolb + ni * 16;
      f32x4 v = acc[mi][ni];
#pragma unroll
      for (int r = 0; r < 4; ++r)
        C[(size_t)(row + r) * N + col] = v[r];
    }
  }
}

// ----------------- full-N adj GEMM (gemmA, BM=128, BN=N) -------------------
// split-K=2, grid 256, kc-per-XCD map; ring-3 counted structure (R7) +
// NEW: slot-XOR swizzle (pre-swizzled gload source, swizzled reads).
template <int NI>
__global__ __launch_bounds__(512, 1)
void gemmA(const unsigned short* __restrict__ A, const unsigned short* __restrict__ Bt,
           float* __restrict__ Pp, int M, int N, int K) {
  constexpr int NL = 1 + NI;                     // gloads per tile
  __shared__ __align__(16) unsigned short As[3 * 128 * 32];      // 24 KiB
  __shared__ __align__(16) unsigned short Bs[3 * NI * 128 * 32]; // 96/48 KiB
  const int t = threadIdx.x, l = t & 63, w = t >> 6;

  const int wg = (blockIdx.x & 7) * 32 + (blockIdx.x >> 3);
  const int kc = wg >> 7;                        // 0..1
  const int mb = wg & 127;                       // 0..127
  const int Klen = K >> 1;
  const int koff = kc * Klen;
  const int NT = Klen >> 5;                      // 256
  const int fr = l & 15, fq = l >> 4;
  const int sx = ((fr >> 1) & 3) << 3;           // read-side slot XOR
  const int swz = (((t & 3) ^ ((t >> 3) & 3))) * 8;   // staging source XOR

  const unsigned short* AgR = A  + (size_t)(mb * 128 + (t >> 2)) * K + koff + swz;
  const unsigned short* BgR = Bt + (size_t)(t >> 2) * K + koff + swz;
  unsigned short* AsL = As + t * 8;
  unsigned short* BsL = Bs + t * 8;

#define STAGE_A(s, b)  gload_lds16(AgR + (size_t)(s) * 32, AsL + (b) * 4096);
#define STAGE_B(s, b)                                                         \
  _Pragma("unroll")                                                           \
  for (int j = 0; j < NI; ++j)                                                \
    gload_lds16(BgR + (size_t)(j * 128) * K + (size_t)(s) * 32,               \
                BsL + (b) * NI * 4096 + j * 4096);

  STAGE_A(0, 0) STAGE_B(0, 0)
  STAGE_A(1, 1) STAGE_B(1, 1)
  asm volatile("s_waitcnt vmcnt(%0)" :: "i"(NL) : "memory");
  __builtin_amdgcn_sched_barrier(0);
  __builtin_amdgcn_s_barrier();

  f32x4 acc[8][NI] = {};
  const int aoff = fr * 32;
  const int boff = (w * (NI * 16) + fr) * 32;

  int bb = 0, sb = 2;
  for (int tt = 0; tt < NT; ++tt) {
    const bool stg = (tt + 2) < NT;
    bf16x8 a03[4], a47[4], bf[NI];
#pragma unroll
    for (int mi = 0; mi < 4; ++mi)
      a03[mi] = *(const bf16x8*)&As[bb * 4096 + aoff + mi * 512 + ((fq * 8) ^ sx)];
#pragma unroll
    for (int ni = 0; ni < NI; ++ni)
      bf[ni] = *(const bf16x8*)&Bs[bb * NI * 4096 + boff + ni * 512 + ((fq * 8) ^ sx)];
#pragma unroll
    for (int mi = 0; mi < 4; ++mi)
      a47[mi] = *(const bf16x8*)&As[bb * 4096 + aoff + 2048 + mi * 512 + ((fq * 8) ^ sx)];
    if (stg) { STAGE_A(tt + 2, sb) }
    asm volatile("s_waitcnt lgkmcnt(4)" ::: "memory");
    __builtin_amdgcn_sched_barrier(0);
    __builtin_amdgcn_s_setprio(1);
#pragma unroll
    for (int mi = 0; mi < 4; ++mi)
#pragma unroll
      for (int ni = 0; ni < NI; ++ni)
        acc[mi][ni] = __builtin_amdgcn_mfma_f32_16x16x32_bf16(a03[mi], bf[ni],
                                                              acc[mi][ni], 0, 0, 0);
    __builtin_amdgcn_s_setprio(0);
    asm volatile("s_waitcnt lgkmcnt(0)" ::: "memory");
    __builtin_amdgcn_sched_barrier(0);
    __builtin_amdgcn_s_setprio(1);
#pragma unroll
    for (int mi = 0; mi < 4; ++mi)
#pragma unroll
      for (int ni = 0; ni < NI; ++ni)
        acc[mi + 4][ni] = __builtin_amdgcn_mfma_f32_16x16x32_bf16(a47[mi], bf[ni],
                                                                  acc[mi + 4][ni], 0, 0, 0);
    __builtin_amdgcn_s_setprio(0);
    if (stg) { STAGE_B(tt + 2, sb) }
    if (stg) {
      asm volatile("s_waitcnt vmcnt(%0)" :: "i"(NL) : "memory");
    } else {
      asm volatile("s_waitcnt vmcnt(0)" ::: "memory");
    }
    __builtin_amdgcn_sched_barrier(0);
    __builtin_amdgcn_s_barrier();
    bb = (bb == 2) ? 0 : bb + 1;
    sb = (sb == 2) ? 0 : sb + 1;
  }
#undef STAGE_B
#undef STAGE_A

  float* C = Pp + (size_t)kc * M * N;
  const int growb = mb * 128 + fq * 4;
  const int gcolb = w * (NI * 16) + fr;
#pragma unroll
  for (int mi = 0; mi < 8; ++mi) {
    int row = growb + mi * 16;
#pragma unroll
    for (int ni = 0; ni < NI; ++ni) {
      int col = gcolb + ni * 16;
      f32x4 v = acc[mi][ni];
#pragma unroll
      for (int r = 0; r < 4; ++r)
        C[(size_t)(row + r) * N + col] = v[r];
    }
  }
}

// ------------------------------ main GEMM ----------------------------------
// (unchanged 2-phase kernel; used for G1/G3/G5 + no-adjb fallback)
template <int EP, bool ABF16>
__global__ __launch_bounds__(256, 2)
void gemm_bt(const void* __restrict__ Av, const unsigned short* __restrict__ Bt,
             void* __restrict__ Cout, const float* __restrict__ bias,
             int M, int N, int K, int nbx, int Klen) {
  __shared__ __align__(16) unsigned short As[128 * 64];
  __shared__ __align__(16) unsigned short Bs[128 * 64];
  const int t = threadIdx.x;
  const int l = t & 63;
  const int w = t >> 6;

  int wg = blockIdx.x;
  const int cpx = gridDim.x >> 3;
  wg = (wg & 7) * cpx + (wg >> 3);
  const int mb = wg / nbx, nb = wg % nbx;
  const int kc = blockIdx.y;
  const int koff = kc * Klen;

  const int wr = w >> 1, wc = w & 1;
  f32x4 acc[4][4] = {};

  const int srow = w * 8 + (l >> 3);
  const int sk0  = 8 * ((l & 7) ^ (l >> 3));
  const unsigned short* Bg = Bt + (size_t)(nb * 128 + srow) * K + koff + sk0;
  unsigned short* BsL = Bs + w * 512 + l * 8;
  unsigned short* AsL = As + w * 512 + l * 8;

  const unsigned short* Ag16 = nullptr;
  const float* Ag32 = nullptr;
  unsigned short* AsWr = nullptr;
  int ak = 0, axm = 0;
  if constexpr (ABF16) {
    Ag16 = (const unsigned short*)Av + (size_t)(mb * 128 + srow) * K + koff + sk0;
  } else {
    const int ar = t >> 1;
    ak = (t & 1) * 32;
    axm = (ar & 7) << 3;
    Ag32 = (const float*)Av + (size_t)(mb * 128 + ar) * K + koff + ak;
    AsWr = As + ar * 64;
  }

  const int fr = l & 15, fq = l >> 4;
  const int rxor = (fr & 7) << 3;

  const int steps = Klen >> 6;
  for (int kb = 0; kb < steps; ++kb) {
#pragma unroll
    for (int i = 0; i < 4; ++i)
      gload_lds16(Bg + (size_t)i * 32 * K, BsL + i * 2048);
    Bg += 64;
    if constexpr (ABF16) {
#pragma unroll
      for (int i = 0; i < 4; ++i)
        gload_lds16(Ag16 + (size_t)i * 32 * K, AsL + i * 2048);
      Ag16 += 64;
    } else {
#pragma unroll
      for (int q = 0; q < 4; ++q) {
        float4 c0 = ((const float4*)Ag32)[q * 2];
        float4 c1 = ((const float4*)Ag32)[q * 2 + 1];
        u16x8 v;
        v[0] = f2bf(c0.x); v[1] = f2bf(c0.y); v[2] = f2bf(c0.z); v[3] = f2bf(c0.w);
        v[4] = f2bf(c1.x); v[5] = f2bf(c1.y); v[6] = f2bf(c1.z); v[7] = f2bf(c1.w);
        *(u16x8*)&AsWr[(ak + q * 8) ^ axm] = v;
      }
      Ag32 += 64;
    }
    __syncthreads();

    bf16x8 af[2][4], bfr[2][4];
#pragma unroll
    for (int kk = 0; kk < 2; ++kk) {
#pragma unroll
      for (int mi = 0; mi < 4; ++mi) {
        int arow = wr * 64 + mi * 16 + fr;
        af[kk][mi] = *(const bf16x8*)&As[arow * 64 + ((kk * 32 + fq * 8) ^ rxor)];
      }
#pragma unroll
      for (int ni = 0; ni < 4; ++ni) {
        int brow = wc * 64 + ni * 16 + fr;
        bfr[kk][ni] = *(const bf16x8*)&Bs[brow * 64 + ((kk * 32 + fq * 8) ^ rxor)];
      }
    }
#pragma unroll
    for (int kk = 0; kk < 2; ++kk)
#pragma unroll
      for (int mi = 0; mi < 4; ++mi)
#pragma unroll
        for (int ni = 0; ni < 4; ++ni)
          acc[mi][ni] = __builtin_amdgcn_mfma_f32_16x16x32_bf16(af[kk][mi], bfr[kk][ni],
                                                                acc[mi][ni], 0, 0, 0);
    __syncthreads();
  }

  const int r0 = fq * 4;
  const int c0 = fr;
  const int growb = mb * 128 + wr * 64 + r0;
  const int gcolb = nb * 128 + wc * 64 + c0;
  if constexpr (EP == 0) {
    unsigned short* Ct = (unsigned short*)Cout;  // [N][M] bf16
#pragma unroll
    for (int ni = 0; ni < 4; ++ni) {
      int col = gcolb + ni * 16;
#pragma unroll
      for (int mi = 0; mi < 4; ++mi) {
        int row = growb + mi * 16;
        f32x4 v = acc[mi][ni];
        u16x4 o;
        o[0] = f2bf(v[0]); o[1] = f2bf(v[1]); o[2] = f2bf(v[2]); o[3] = f2bf(v[3]);
        *(u16x4*)&Ct[(size_t)col * M + row] = o;
      }
    }
  } else if constexpr (EP == 1) {
    unsigned short* C = (unsigned short*)Cout;  // [M][N] bf16, relu(.+bias)
#pragma unroll
    for (int ni = 0; ni < 4; ++ni) {
      int col = gcolb + ni * 16;
      float b = bias[col];
#pragma unroll
      for (int mi = 0; mi < 4; ++mi) {
        int row = growb + mi * 16;
        f32x4 v = acc[mi][ni];
#pragma unroll
        for (int r = 0; r < 4; ++r)
          C[(size_t)(row + r) * N + col] = f2bf(fmaxf(v[r] + b, 0.0f));
      }
    }
  } else {  // EP == 3: split-K fp32 partial
    float* C = (float*)Cout + (size_t)kc * M * N;
#pragma unroll
    for (int ni = 0; ni < 4; ++ni) {
      int col = gcolb + ni * 16;
#pragma unroll
      for (int mi = 0; mi < 4; ++mi) {
        int row = growb + mi * 16;
        f32x4 v = acc[mi][ni];
#pragma unroll
        for (int r = 0; r < 4; ++r)
          C[(size_t)(row + r) * N + col] = v[r];
      }
    }
  }
}

// ------------------------------ head kernel --------------------------------
__global__ __launch_bounds__(256, 2)
void head_kernel(const unsigned short* __restrict__ EMB, const int* __restrict__ tf,
                 const int* __restrict__ gi, const unsigned short* __restrict__ Wh1t,
                 const float* __restrict__ bh1, const float* __restrict__ Wh2,
                 const float* __restrict__ bh2, float* __restrict__ out, int P) {
  __shared__ __align__(16) union SU {
    struct { unsigned short As[64 * 64]; unsigned short Bs[256 * 64]; } s;
    unsigned short hdn[64 * 264];
  } u;
  __shared__ float wh2s[256 * 3];
  const int t = threadIdx.x, l = t & 63, w = t >> 6;
  const int pb = blockIdx.x;

  wh2s[t]       = Wh2[t];
  wh2s[t + 256] = Wh2[t + 256];
  wh2s[t + 512] = Wh2[t + 512];

  const int srow = w * 8 + (l >> 3);
  const int sk0  = 8 * ((l & 7) ^ (l >> 3));
  size_t tfo[2], gio[2];
#pragma unroll
  for (int i = 0; i < 2; ++i) {
    int p = pb * 64 + i * 32 + srow;
    if (p >= P) p = P - 1;
    tfo[i] = (size_t)tf[p] * 256;
    gio[i] = (size_t)gi[p] * 256;
  }
  const unsigned short* BgB = Wh1t + (size_t)srow * 512 + sk0;
  unsigned short* AsL = u.s.As + w * 512 + l * 8;
  unsigned short* BsL = u.s.Bs + w * 512 + l * 8;

  const int fr = l & 15, fq = l >> 4;
  const int rxor = (fr & 7) << 3;

  f32x4 acc[4][4] = {};
  for (int kb = 0; kb < 8; ++kb) {
    const int klo = (kb & 3) * 64 + sk0;
#pragma unroll
    for (int i = 0; i < 2; ++i)
      gload_lds16(EMB + ((kb < 4) ? tfo[i] : gio[i]) + klo, AsL + i * 2048);
#pragma unroll
    for (int i = 0; i < 8; ++i)
      gload_lds16(BgB + (size_t)i * 32 * 512 + kb * 64, BsL + i * 2048);
    __syncthreads();

    bf16x8 af[2][4], bfr[2][4];
#pragma unroll
    for (int kk = 0; kk < 2; ++kk) {
#pragma unroll
      for (int mi = 0; mi < 4; ++mi) {
        int arow = mi * 16 + fr;
        af[kk][mi] = *(const bf16x8*)&u.s.As[arow * 64 + ((kk * 32 + fq * 8) ^ rxor)];
      }
#pragma unroll
      for (int ni = 0; ni < 4; ++ni) {
        int brow = w * 64 + ni * 16 + fr;
        bfr[kk][ni] = *(const bf16x8*)&u.s.Bs[brow * 64 + ((kk * 32 + fq * 8) ^ rxor)];
      }
    }
#pragma unroll
    for (int kk = 0; kk < 2; ++kk)
#pragma unroll
      for (int mi = 0; mi < 4; ++mi)
#pragma unroll
        for (int ni = 0; ni < 4; ++ni)
          acc[mi][ni] = __builtin_amdgcn_mfma_f32_16x16x32_bf16(af[kk][mi], bfr[kk][ni],
                                                                acc[mi][ni], 0, 0, 0);
    __syncthreads();
  }

  const int r0 = fq * 4, c0 = fr;
#pragma unroll
  for (int ni = 0; ni < 4; ++ni) {
    int col = w * 64 + ni * 16 + c0;
    float b = bh1[col];
#pragma unroll
    for (int mi = 0; mi < 4; ++mi) {
      int row = mi * 16 + r0;
      f32x4 v = acc[mi][ni];
#pragma unroll
      for (int r = 0; r < 4; ++r) {
        float xv = v[r] + b;
        float g = 0.5f * xv * (1.0f + erff(xv * 0.70710678118f));
        u.hdn[(row + r) * 264 + col] = f2bf(g);
      }
    }
  }
  __syncthreads();

  const int pl = w * 16 + (l >> 2);
  const int pg = pb * 64 + pl;
  const int ks = (l & 3) * 64;
  float a0 = 0.f, a1 = 0.f, a2 = 0.f;
  const unsigned short* hr = u.hdn + pl * 264 + ks;
#pragma unroll
  for (int kq = 0; kq < 8; ++kq) {
    u16x8 hv = *(const u16x8*)(hr + kq * 8);
#pragma unroll
    for (int j = 0; j < 8; ++j) {
      float h = bf2f(hv[j]);
      int k = ks + kq * 8 + j;
      a0 = fmaf(h, wh2s[k * 3 + 0], a0);
      a1 = fmaf(h, wh2s[k * 3 + 1], a1);
      a2 = fmaf(h, wh2s[k * 3 + 2], a2);
    }
  }
  a0 += __shfl_xor(a0, 1); a0 += __shfl_xor(a0, 2);
  a1 += __shfl_xor(a1, 1); a1 += __shfl_xor(a1, 2);
  a2 += __shfl_xor(a2, 1); a2 += __shfl_xor(a2, 2);
  if ((l & 3) == 0 && pg < P) {
    out[(size_t)pg * 3 + 0] = a0 + bh2[0];
    out[(size_t)pg * 3 + 1] = a1 + bh2[1];
    out[(size_t)pg * 3 + 2] = a2 + bh2[2];
  }
}

// ------------------------------- launcher ----------------------------------

extern "C" void kernel_launch(void* const* d_in, const int* in_sizes, int n_in,
                              void* d_out, int out_size, void* d_ws, size_t ws_size,
                              hipStream_t stream) {
  const float* x   = (const float*)d_in[0];
  const float* adj = (const float*)d_in[1];
  const int*   tf  = (const int*)d_in[2];
  const int*   gi  = (const int*)d_in[3];
  const float* W0  = (const float*)d_in[4];
  const float* b0  = (const float*)d_in[5];
  const float* W1  = (const float*)d_in[6];
  const float* b1  = (const float*)d_in[7];
  const float* W2  = (const float*)d_in[8];
  const float* b2  = (const float*)d_in[9];
  const float* Wh1 = (const float*)d_in[10];
  const float* bh1 = (const float*)d_in[11];
  const float* Wh2 = (const float*)d_in[12];
  const float* bh2 = (const float*)d_in[13];
  float* out = (float*)d_out;

  const int NN = 16384;
  const int P = in_sizes[2];  // 100000

  char* ws = (char*)d_ws;
  size_t off = 0;
  auto alloc = [&](size_t bytes) -> char* {
    char* p = ws + off;
    off += (bytes + 255) & ~(size_t)255;
    return p;
  };
  unsigned short* W0t  = (unsigned short*)alloc((size_t)512 * 1024 * 2);
  unsigned short* W1t  = (unsigned short*)alloc((size_t)512 * 512 * 2);
  unsigned short* W2t  = (unsigned short*)alloc((size_t)256 * 512 * 2);
  unsigned short* Wh1t = (unsigned short*)alloc((size_t)256 * 512 * 2);
  unsigned short* Tt   = (unsigned short*)alloc((size_t)512 * NN * 2);  // T0t/T1t/T2t
  unsigned short* H    = (unsigned short*)alloc((size_t)NN * 512 * 2);  // H0/H1 bf16
  unsigned short* EMB  = (unsigned short*)alloc((size_t)NN * 256 * 2);
  float*          Pp   = (float*)alloc((size_t)2 * NN * 512 * 4);       // split-K partials (64 MiB)
  size_t base_end = off;

  bool useAdjB = false;
  unsigned short* adjb = nullptr;
  if (ws_size >= base_end + (size_t)NN * NN * 2) {
    adjb = (unsigned short*)alloc((size_t)NN * NN * 2);
    useAdjB = true;
  }

  // weight transpose+convert (tiny)
  tcvt_kernel<<<dim3((1024 * 512 + 255) / 256), 256, 0, stream>>>(W0, W0t, 1024, 512);
  tcvt_kernel<<<dim3((512 * 512 + 255) / 256), 256, 0, stream>>>(W1, W1t, 512, 512);
  tcvt_kernel<<<dim3((512 * 256 + 255) / 256), 256, 0, stream>>>(W2, W2t, 512, 256);
  tcvt_kernel<<<dim3((512 * 256 + 255) / 256), 256, 0, stream>>>(Wh1, Wh1t, 512, 256);

  // G1: T0t = (x @ W0)^T                       [512][16384] bf16
  gemm_bt<0, false><<<dim3(512), 256, 0, stream>>>(x, W0t, Tt, nullptr,
                                                   NN, 512, 1024, 4, 1024);
  // G2: H0 = relu(adj @ T0 + b0)  [fused fp32-adj convert + adjb side-write]
  if (useAdjB) {
    gemmAF<4><<<dim3(256), 512, 0, stream>>>(adj, Tt, Pp, adjb, NN, 512, NN);
    reduceK_kernel<2, true><<<dim3(8192), 256, 0, stream>>>(Pp, b0, H, NN * 512, 511);
  } else {
    gemm_bt<1, false><<<dim3(512), 256, 0, stream>>>(adj, Tt, H, b0,
                                                     NN, 512, NN, 4, NN);
  }
  // G3: T1t = (H0 @ W1)^T
  gemm_bt<0, true><<<dim3(512), 256, 0, stream>>>(H, W1t, Tt, nullptr,
                                                  NN, 512, 512, 4, 512);
  // G4: H1 = relu(adj @ T1 + b1)
  if (useAdjB) {
    gemmA<4><<<dim3(256), 512, 0, stream>>>(adjb, Tt, Pp, NN, 512, NN);
    reduceK_kernel<2, true><<<dim3(8192), 256, 0, stream>>>(Pp, b1, H, NN * 512, 511);
  } else {
    gemm_bt<1, false><<<dim3(512), 256, 0, stream>>>(adj, Tt, H, b1,
                                                     NN, 512, NN, 4, NN);
  }
  // G5: T2t = (H1 @ W2)^T                      [256][16384] bf16
  gemm_bt<0, true><<<dim3(256), 256, 0, stream>>>(H, W2t, Tt, nullptr,
                                                  NN, 256, 512, 2, 512);
  // G6: EMB = adj @ T2 + b2                    split-K=2 fp32 partials
  if (useAdjB) {
    gemmA<2><<<dim3(256), 512, 0, stream>>>(adjb, Tt, Pp, NN, 256, NN);
    reduceK_kernel<2, false><<<dim3(4096), 256, 0, stream>>>(Pp, b2, EMB, NN * 256, 255);
  } else {
    gemm_bt<3, false><<<dim3(256, 2), 256, 0, stream>>>(adj, Tt, Pp, nullptr,
                                                        NN, 256, NN, 2, NN / 2);
    reduceK_kernel<2, false><<<dim3(4096), 256, 0, stream>>>(Pp, b2, EMB, NN * 256, 255);
  }
  // head: gather + MLP + logits
  head_kernel<<<dim3((P + 63) / 64), 256, 0, stream>>>(EMB, tf, gi, Wh1t, bh1,
                                                       Wh2, bh2, out, P);
}